// Round 17
// baseline (161.994 us; speedup 1.0000x reference)
//
#include <hip/hip_runtime.h>
#include <math.h>

#define IN_CH 128
#define H1N 8
#define C1N 16
#define C2N 64
#define NEG_SLOPE 0.2f

#define BKT_SHIFT 7                 // 128 nodes per bucket
#define BKT_NODES (1 << BKT_SHIFT)
#define NBLK 256                    // blocks for count/bin passes (all CUs)

typedef unsigned short ushortT;
typedef unsigned char ucharT;
typedef short bf16x8 __attribute__((ext_vector_type(8)));
typedef float f32x4 __attribute__((ext_vector_type(4)));
typedef ushortT us8 __attribute__((ext_vector_type(8)));

__device__ __forceinline__ ushortT f2bf(float f) {
    unsigned u = __float_as_uint(f);
    unsigned r = u + 0x7FFFu + ((u >> 16) & 1u);
    return (ushortT)(r >> 16);
}
__device__ __forceinline__ float bf2f(ushortT b) {
    return __uint_as_float(((unsigned)b) << 16);
}
__device__ __forceinline__ float leaky(float x) {
    return (x > 0.f) ? x : NEG_SLOPE * x;
}
__device__ __forceinline__ ucharT f2fp8(float f) {
    unsigned r = (unsigned)__builtin_amdgcn_cvt_pk_fp8_f32(f, 0.f, 0, false);
    return (ucharT)(r & 0xFFu);
}

// ---------------- CSR build: deterministic counting sort, no global-cursor atomics ----------------

__global__ __launch_bounds__(512) void k_cnt(const int* __restrict__ dst,
                                             int E, int N, int* __restrict__ cnt) {
    __shared__ int hist[512];
    int blk = blockIdx.x, t = threadIdx.x;
    int nb = (N + BKT_NODES - 1) >> BKT_SHIFT;
    if (t < nb) hist[t] = 0;
    __syncthreads();
    int Etot = E + N;
    int chunk = (Etot + gridDim.x - 1) / gridDim.x;
    int lo = blk * chunk;
    int hi = lo + chunk; if (hi > Etot) hi = Etot;
    for (int i = lo + t; i < hi; i += 512) {
        int d = (i < E) ? dst[i] : (i - E);
        atomicAdd(&hist[d >> BKT_SHIFT], 1);
    }
    __syncthreads();
    if (t < nb) cnt[t * NBLK + blk] = hist[t];
}

// per bucket: exclusive scan of its NBLK block-counts (in place) + bucket total.
// Last block to finish also scans bucket totals -> bBase, offsets[N].
__global__ __launch_bounds__(NBLK) void k_scanrel(int* __restrict__ cnt,
                                                  int* __restrict__ bucketTotal,
                                                  int nb, int* __restrict__ done,
                                                  int* __restrict__ bBase,
                                                  int N, int* __restrict__ offsets) {
    __shared__ int sh[NBLK];
    __shared__ int isLast;
    int b = blockIdx.x, t = threadIdx.x;
    sh[t] = cnt[b * NBLK + t];
    __syncthreads();
    for (int off = 1; off < NBLK; off <<= 1) {
        int v = (t >= off) ? sh[t - off] : 0;
        __syncthreads();
        sh[t] += v;
        __syncthreads();
    }
    if (t == NBLK - 1) bucketTotal[b] = sh[t];
    cnt[b * NBLK + t] = (t == 0) ? 0 : sh[t - 1];

    __threadfence();
    if (t == 0) isLast = (atomicAdd(done, 1) == gridDim.x - 1) ? 1 : 0;
    __syncthreads();
    if (isLast) {
        __threadfence();                       // acquire others' bucketTotal writes
        __shared__ int sb[2 * NBLK];           // 512 slots >= nb
        sb[t]        = (t < nb) ? bucketTotal[t] : 0;
        sb[t + NBLK] = (t + NBLK < nb) ? bucketTotal[t + NBLK] : 0;
        __syncthreads();
        for (int off = 1; off < 2 * NBLK; off <<= 1) {
            int v0 = (t >= off) ? sb[t - off] : 0;
            int v1 = (t + NBLK >= off) ? sb[t + NBLK - off] : 0;
            __syncthreads();
            sb[t] += v0;
            sb[t + NBLK] += v1;
            __syncthreads();
        }
        if (t < nb) bBase[t] = (t == 0) ? 0 : sb[t - 1];
        if (t + NBLK < nb) bBase[t + NBLK] = sb[t + NBLK - 1];
        if (t == NBLK - 1) {
            int total = sb[2 * NBLK - 1];
            bBase[nb] = total;
            offsets[N] = total;
        }
    }
}

__global__ __launch_bounds__(512) void k_bin(const int* __restrict__ src,
                                             const int* __restrict__ dst,
                                             int E, int N,
                                             const int* __restrict__ cnt,
                                             const int* __restrict__ bBase,
                                             unsigned* __restrict__ pair) {
    __shared__ int cur[512];
    int blk = blockIdx.x, t = threadIdx.x;
    int nb = (N + BKT_NODES - 1) >> BKT_SHIFT;
    if (t < nb) cur[t] = bBase[t] + cnt[t * NBLK + blk];
    __syncthreads();
    int Etot = E + N;
    int chunk = (Etot + gridDim.x - 1) / gridDim.x;
    int lo = blk * chunk;
    int hi = lo + chunk; if (hi > Etot) hi = Etot;
    for (int i = lo + t; i < hi; i += 512) {
        int s, d;
        if (i < E) { s = src[i]; d = dst[i]; }
        else       { s = d = i - E; }
        int b = d >> BKT_SHIFT;
        int pos = atomicAdd(&cur[b], 1);
        pair[pos] = ((unsigned)(d & (BKT_NODES - 1)) << 16) | (unsigned)s;
    }
}

__global__ __launch_bounds__(256) void k_csr_local(const unsigned* __restrict__ pair,
                                                   const int* __restrict__ bBase,
                                                   int N, int* __restrict__ offsets,
                                                   ushortT* __restrict__ csr) {
    __shared__ int hist[BKT_NODES];
    __shared__ int loff[BKT_NODES];
    int b = blockIdx.x;
    int t = threadIdx.x;
    int base = bBase[b];
    int cnt = bBase[b + 1] - base;
    const unsigned* pp = pair + base;

    if (t < BKT_NODES) hist[t] = 0;
    __syncthreads();
    for (int i = t; i < cnt; i += 256) atomicAdd(&hist[pp[i] >> 16], 1);
    __syncthreads();
    if (t < BKT_NODES) loff[t] = hist[t];
    __syncthreads();
    for (int off = 1; off < BKT_NODES; off <<= 1) {
        int v = 0;
        if (t < BKT_NODES && t >= off) v = loff[t - off];
        __syncthreads();
        if (t < BKT_NODES) loff[t] += v;
        __syncthreads();
    }
    int node0 = b << BKT_SHIFT;
    if (t < BKT_NODES) {
        int excl = (t == 0) ? 0 : loff[t - 1];
        hist[t] = excl;
        int g = node0 + t;
        if (g < N) offsets[g] = base + excl;
    }
    __syncthreads();
    for (int i = t; i < cnt; i += 256) {
        unsigned pk = pp[i];
        int pos = atomicAdd(&hist[pk >> 16], 1);
        csr[base + pos] = (ushortT)(pk & 0xFFFFu);
    }
}

// ---------------- one-shot W transpose+cast (both weights in one launch) ----------------

__global__ void k_wcast(const float* __restrict__ W1, const float* __restrict__ W2,
                        ushortT* __restrict__ W1t, ushortT* __restrict__ W2t) {
    int id = blockIdx.x * blockDim.x + threadIdx.x;
    if (id < IN_CH * IN_CH) {
        int n = id / IN_CH, k = id % IN_CH;
        W1t[id] = f2bf(W1[(size_t)k * IN_CH + n]);
    } else if (id < IN_CH * IN_CH + IN_CH * C2N) {
        int id2 = id - IN_CH * IN_CH;
        int n = id2 / IN_CH, k = id2 % IN_CH;
        W2t[id2] = f2bf(W2[(size_t)k * C2N + n]);
    }
}

// ---------------- MFMA GEMM (bf16) + fused attention coefficients ----------------
// C = A @ W; BM=128 rows/block, 4 waves x 2 strips; W pre-transposed bf16.
// OUT8: store C as fp8 e4m3; else bf16.
// C/D layout: col=lane&15, row=(lane>>4)*4+reg (validated R13).

template <int KOUT, int HEADS, bool BFIN, bool OUT8>
__global__ __launch_bounds__(256) void k_gemm_att(const void* __restrict__ Av,
                                                  const ushortT* __restrict__ Wt,
                                                  const float* __restrict__ att_s,
                                                  const float* __restrict__ att_d,
                                                  int N, void* __restrict__ Cout,
                                                  float* __restrict__ as_,
                                                  float* __restrict__ ad_) {
    constexpr int NT = KOUT / 16;
    constexpr int LDK = IN_CH + 8;
    __shared__ ushortT Alds[128][LDK];
    __shared__ ushortT Wlds[KOUT][LDK];
    int t = threadIdx.x;
    int row0 = blockIdx.x * 128;
    int w    = t >> 6;
    int lane = t & 63;
    int lm   = lane & 15;
    int lg   = lane >> 4;

    if constexpr (BFIN) {
        for (int idx = t; idx < 128 * 16; idx += 256) {
            int r  = idx >> 4;
            int c8 = (idx & 15) << 3;
            int gr = row0 + r;
            us8 u = (us8){0,0,0,0,0,0,0,0};
            if (gr < N) u = *(const us8*)((const ushortT*)Av + (size_t)gr * IN_CH + c8);
            *(us8*)(&Alds[r][c8]) = u;
        }
    } else {
        for (int idx = t; idx < 128 * 32; idx += 256) {
            int r  = idx >> 5;
            int c4 = (idx & 31) << 2;
            int gr = row0 + r;
            ushort4 u; u.x = 0; u.y = 0; u.z = 0; u.w = 0;
            if (gr < N) {
                float4 v = *(const float4*)((const float*)Av + (size_t)gr * IN_CH + c4);
                u.x = f2bf(v.x); u.y = f2bf(v.y); u.z = f2bf(v.z); u.w = f2bf(v.w);
            }
            *(ushort4*)(&Alds[r][c4]) = u;
        }
    }
    for (int idx = t; idx < KOUT * 16; idx += 256) {
        int n  = idx >> 4;
        int kb = (idx & 15) << 3;
        *(us8*)(&Wlds[n][kb]) = *(const us8*)(Wt + (size_t)n * IN_CH + kb);
    }
    __syncthreads();

    f32x4 acc[2][NT];
#pragma unroll
    for (int s = 0; s < 2; ++s)
#pragma unroll
        for (int ct = 0; ct < NT; ++ct) acc[s][ct] = (f32x4){0.f, 0.f, 0.f, 0.f};

#pragma unroll
    for (int s = 0; s < 2; ++s) {
        int ar = w * 32 + s * 16 + lm;
#pragma unroll
        for (int ks = 0; ks < 4; ++ks) {
            int kb = ks * 32 + lg * 8;
            bf16x8 af = *(const bf16x8*)(&Alds[ar][kb]);
#pragma unroll
            for (int ct = 0; ct < NT; ++ct) {
                bf16x8 bf = *(const bf16x8*)(&Wlds[ct * 16 + lm][kb]);
                acc[s][ct] = __builtin_amdgcn_mfma_f32_16x16x32_bf16(af, bf, acc[s][ct], 0, 0, 0);
            }
        }
    }

#pragma unroll
    for (int s = 0; s < 2; ++s) {
        int rb = row0 + w * 32 + s * 16 + lg * 4;
        float asp0 = 0.f, asp1 = 0.f, asp2 = 0.f, asp3 = 0.f;
        float adp0 = 0.f, adp1 = 0.f, adp2 = 0.f, adp3 = 0.f;
#pragma unroll
        for (int ct = 0; ct < NT; ++ct) {
            int gcol = ct * 16 + lm;
            float sc = att_s[gcol];
            float dc = att_d[gcol];
            float c0 = acc[s][ct][0], c1 = acc[s][ct][1];
            float c2 = acc[s][ct][2], c3 = acc[s][ct][3];
#pragma unroll
            for (int i = 0; i < 4; ++i) {
                int gr = rb + i;
                if (gr < N) {
                    if constexpr (OUT8) {
                        ((ucharT*)Cout)[(size_t)gr * KOUT + gcol] = f2fp8(acc[s][ct][i]);
                    } else {
                        ((ushortT*)Cout)[(size_t)gr * KOUT + gcol] = f2bf(acc[s][ct][i]);
                    }
                }
            }
            if constexpr (HEADS == 1) {
                asp0 = fmaf(c0, sc, asp0); asp1 = fmaf(c1, sc, asp1);
                asp2 = fmaf(c2, sc, asp2); asp3 = fmaf(c3, sc, asp3);
                adp0 = fmaf(c0, dc, adp0); adp1 = fmaf(c1, dc, adp1);
                adp2 = fmaf(c2, dc, adp2); adp3 = fmaf(c3, dc, adp3);
            } else {
                float r0 = c0 * sc, r1 = c1 * sc, r2 = c2 * sc, r3 = c3 * sc;
                float q0 = c0 * dc, q1 = c1 * dc, q2 = c2 * dc, q3 = c3 * dc;
#pragma unroll
                for (int off = 1; off < 16; off <<= 1) {
                    r0 += __shfl_xor(r0, off); r1 += __shfl_xor(r1, off);
                    r2 += __shfl_xor(r2, off); r3 += __shfl_xor(r3, off);
                    q0 += __shfl_xor(q0, off); q1 += __shfl_xor(q1, off);
                    q2 += __shfl_xor(q2, off); q3 += __shfl_xor(q3, off);
                }
                if (lm == 0) {
                    if (rb + 0 < N) { as_[(size_t)(rb + 0) * HEADS + ct] = r0; ad_[(size_t)(rb + 0) * HEADS + ct] = q0; }
                    if (rb + 1 < N) { as_[(size_t)(rb + 1) * HEADS + ct] = r1; ad_[(size_t)(rb + 1) * HEADS + ct] = q1; }
                    if (rb + 2 < N) { as_[(size_t)(rb + 2) * HEADS + ct] = r2; ad_[(size_t)(rb + 2) * HEADS + ct] = q2; }
                    if (rb + 3 < N) { as_[(size_t)(rb + 3) * HEADS + ct] = r3; ad_[(size_t)(rb + 3) * HEADS + ct] = q3; }
                }
            }
        }
        if constexpr (HEADS == 1) {
#pragma unroll
            for (int off = 1; off < 16; off <<= 1) {
                asp0 += __shfl_xor(asp0, off); asp1 += __shfl_xor(asp1, off);
                asp2 += __shfl_xor(asp2, off); asp3 += __shfl_xor(asp3, off);
                adp0 += __shfl_xor(adp0, off); adp1 += __shfl_xor(adp1, off);
                adp2 += __shfl_xor(adp2, off); adp3 += __shfl_xor(adp3, off);
            }
            if (lm == 0) {
                if (rb + 0 < N) { as_[rb + 0] = asp0; ad_[rb + 0] = adp0; }
                if (rb + 1 < N) { as_[rb + 1] = asp1; ad_[rb + 1] = adp1; }
                if (rb + 2 < N) { as_[rb + 2] = asp2; ad_[rb + 2] = adp2; }
                if (rb + 3 < N) { as_[rb + 3] = asp3; ad_[rb + 3] = adp3; }
            }
        }
    }
}

// ---------------- layer 1 aggregation (+bias +ELU) ----------------
// h1 fp8 e4m3 (128 B/row); lane reads ushort = 2 fp8, HW cvt. Output bf16.

__global__ void k_agg1(const ucharT* __restrict__ h1f8,
                       const float* __restrict__ as1, const float* __restrict__ ad1,
                       const int* __restrict__ offsets, const ushortT* __restrict__ csr,
                       const float* __restrict__ b1,
                       int N, ushortT* __restrict__ h2in) {
    int wid  = (blockIdx.x * blockDim.x + threadIdx.x) >> 6;
    int lane = threadIdx.x & 63;
    if (wid >= N) return;
    int v = wid;
    int hc = lane >> 3;
    int hp = lane & 7;
    float adc = ad1[v * H1N + hc];
    float adp = ad1[v * H1N + hp];
    float denom = 0.f, acc0 = 0.f, acc1 = 0.f;
    int beg = offsets[v], end = offsets[v + 1];
    int j = beg;
    for (; j + 8 <= end; j += 8) {
        int ep = lane >> 3;
        int sE = csr[j + ep];
        float a = as1[sE * H1N + hp];
        float pp = __expf(leaky(a + adp));
#pragma unroll
        for (int e = 0; e < 8; ++e) {
            int srcl = e * 8 + hc;
            float pe = __shfl(pp, srcl);
            int   se = __shfl(sE, srcl);
            unsigned q = *(const ushortT*)(h1f8 + (size_t)se * IN_CH + lane * 2);
            float x0 = __builtin_amdgcn_cvt_f32_fp8(q, 0);
            float x1 = __builtin_amdgcn_cvt_f32_fp8(q, 1);
            denom += pe;
            acc0 = fmaf(pe, x0, acc0);
            acc1 = fmaf(pe, x1, acc1);
        }
    }
    if (j + 4 <= end) {
        int ep = (lane >> 3) & 3;
        int sE = csr[j + ep];
        float a = as1[sE * H1N + hp];
        float pp = __expf(leaky(a + adp));
#pragma unroll
        for (int e = 0; e < 4; ++e) {
            int srcl = e * 8 + hc;
            float pe = __shfl(pp, srcl);
            int   se = __shfl(sE, srcl);
            unsigned q = *(const ushortT*)(h1f8 + (size_t)se * IN_CH + lane * 2);
            float x0 = __builtin_amdgcn_cvt_f32_fp8(q, 0);
            float x1 = __builtin_amdgcn_cvt_f32_fp8(q, 1);
            denom += pe;
            acc0 = fmaf(pe, x0, acc0);
            acc1 = fmaf(pe, x1, acc1);
        }
        j += 4;
    }
    for (; j < end; ++j) {
        int s = csr[j];
        float a = as1[s * H1N + hc];
        unsigned q = *(const ushortT*)(h1f8 + (size_t)s * IN_CH + lane * 2);
        float x0 = __builtin_amdgcn_cvt_f32_fp8(q, 0);
        float x1 = __builtin_amdgcn_cvt_f32_fp8(q, 1);
        float p = __expf(leaky(a + adc));
        denom += p;
        acc0 = fmaf(p, x0, acc0);
        acc1 = fmaf(p, x1, acc1);
    }
    float inv = 1.f / (denom + 1e-16f);
    float o0 = acc0 * inv + b1[lane * 2];
    float o1 = acc1 * inv + b1[lane * 2 + 1];
    o0 = (o0 > 0.f) ? o0 : expm1f(o0);
    o1 = (o1 > 0.f) ? o1 : expm1f(o1);
    unsigned pk = ((unsigned)f2bf(o1) << 16) | (unsigned)f2bf(o0);
    *(unsigned*)(h2in + (size_t)v * IN_CH + lane * 2) = pk;
}

// ---------------- layer 2 aggregation (+bias) + log_softmax ----------------

__global__ __launch_bounds__(256) void k_agg2(const ushortT* __restrict__ h2bf,
                       const float* __restrict__ as2, const float* __restrict__ ad2,
                       const int* __restrict__ offsets, const ushortT* __restrict__ csr,
                       const float* __restrict__ b2,
                       int N, float* __restrict__ out) {
    int wid  = (blockIdx.x * blockDim.x + threadIdx.x) >> 6;
    int lane = threadIdx.x & 63;
    int half = lane >> 5;
    int v = wid * 2 + half;
    bool alive = (v < N);
    int c2 = (lane & 31) * 2;

    float ad = 0.f;
    int beg = 0, end = 0;
    if (alive) {
        ad = ad2[v];
        beg = offsets[v];
        end = offsets[v + 1];
    }
    float denom = 0.f, acc0 = 0.f, acc1 = 0.f;
    int j = beg;
    for (; j + 8 <= end; j += 8) {
        int sE = csr[j + (lane & 7)];
        float p = __expf(leaky(as2[sE] + ad));
#pragma unroll
        for (int e = 0; e < 8; ++e) {
            int srcl = (lane & 32) + e;
            float pe = __shfl(p, srcl);
            int   se = __shfl(sE, srcl);
            unsigned q = *(const unsigned*)(h2bf + (size_t)se * C2N + c2);
            denom += pe;
            acc0 = fmaf(pe, bf2f((ushortT)(q & 0xFFFFu)), acc0);
            acc1 = fmaf(pe, bf2f((ushortT)(q >> 16)), acc1);
        }
    }
    if (j < end) {
        int m = end - j;
        int ep = lane & 7;
        int sE = 0;
        float p = 0.f;
        if (ep < m) {
            sE = csr[j + ep];
            p = __expf(leaky(as2[sE] + ad));
        }
        for (int e = 0; e < m; ++e) {
            int srcl = (lane & 32) + e;
            float pe = __shfl(p, srcl);
            int   se = __shfl(sE, srcl);
            unsigned q = *(const unsigned*)(h2bf + (size_t)se * C2N + c2);
            denom += pe;
            acc0 = fmaf(pe, bf2f((ushortT)(q & 0xFFFFu)), acc0);
            acc1 = fmaf(pe, bf2f((ushortT)(q >> 16)), acc1);
        }
    }
    float inv = 1.f / (denom + 1e-16f);
    float o0 = acc0 * inv + b2[c2];
    float o1 = acc1 * inv + b2[c2 + 1];
    float mx = fmaxf(o0, o1);
#pragma unroll
    for (int off = 16; off >= 1; off >>= 1) mx = fmaxf(mx, __shfl_xor(mx, off));
    float se2 = __expf(o0 - mx) + __expf(o1 - mx);
#pragma unroll
    for (int off = 16; off >= 1; off >>= 1) se2 += __shfl_xor(se2, off);
    if (alive) {
        float lse = logf(se2);
        float2 ov; ov.x = o0 - mx - lse; ov.y = o1 - mx - lse;
        *(float2*)(out + (size_t)v * C2N + c2) = ov;
    }
}

// ---------------- launch ----------------

extern "C" void kernel_launch(void* const* d_in, const int* in_sizes, int n_in,
                              void* d_out, int out_size, void* d_ws, size_t ws_size,
                              hipStream_t stream) {
    const float* x      = (const float*)d_in[0];
    const int*   ei     = (const int*)d_in[1];
    const float* W1     = (const float*)d_in[2];
    const float* att_s1 = (const float*)d_in[3];
    const float* att_d1 = (const float*)d_in[4];
    const float* b1     = (const float*)d_in[5];
    const float* W2     = (const float*)d_in[6];
    const float* att_s2 = (const float*)d_in[7];
    const float* att_d2 = (const float*)d_in[8];
    const float* b2     = (const float*)d_in[9];

    int N = in_sizes[0] / IN_CH;
    int E = in_sizes[1] / 2;
    const int* srcA = ei;
    const int* dstA = ei + E;
    int Etot = E + N;
    int nb = (N + BKT_NODES - 1) >> BKT_SHIFT;   // 391 for N=50000 (<= 512)

    char* p = (char*)d_ws;
    auto carve = [&](size_t bytes) {
        void* r = (void*)p;
        p += (bytes + 255) & ~(size_t)255;
        return r;
    };
    ucharT* h1f8  = (ucharT*)carve((size_t)N * IN_CH);
    ushortT* h2bf = (ushortT*)carve((size_t)N * C2N * 2);
    ushortT* h2in = (ushortT*)carve((size_t)N * IN_CH * 2);
    float* as1  = (float*)carve((size_t)N * H1N * 4);
    float* ad1  = (float*)carve((size_t)N * H1N * 4);
    float* as2  = (float*)carve((size_t)N * 4);
    float* ad2  = (float*)carve((size_t)N * 4);
    int* offsets     = (int*)carve((size_t)(N + 1) * 4);
    ushortT* csr     = (ushortT*)carve((size_t)(Etot + 32) * 2);
    int* cnt         = (int*)carve((size_t)nb * NBLK * 4);
    int* bucketTotal = (int*)carve((size_t)nb * 4);
    int* bBase       = (int*)carve((size_t)(nb + 1) * 4);
    int* done        = (int*)carve(256);
    unsigned* pair   = (unsigned*)carve((size_t)Etot * 4);
    ushortT* W1t     = (ushortT*)carve((size_t)IN_CH * IN_CH * 2);
    ushortT* W2t     = (ushortT*)carve((size_t)IN_CH * C2N * 2);

    hipMemsetAsync(done, 0, 4, stream);

    // one-shot weight transpose+cast (both weights)
    k_wcast<<<(IN_CH * IN_CH + IN_CH * C2N + 255) / 256, 256, 0, stream>>>(W1, W2, W1t, W2t);

    // CSR build (deterministic counting sort; no global-cursor atomics)
    k_cnt<<<NBLK, 512, 0, stream>>>(dstA, E, N, cnt);
    k_scanrel<<<nb, NBLK, 0, stream>>>(cnt, bucketTotal, nb, done, bBase, N, offsets);
    k_bin<<<NBLK, 512, 0, stream>>>(srcA, dstA, E, N, cnt, bBase, pair);
    k_csr_local<<<nb, 256, 0, stream>>>(pair, bBase, N, offsets, csr);

    // layer 1 (h1 stored fp8 e4m3)
    k_gemm_att<128, 8, false, true><<<(N + 127) / 128, 256, 0, stream>>>(
        x, W1t, att_s1, att_d1, N, h1f8, as1, ad1);
    k_agg1<<<(N * 64 + 255) / 256, 256, 0, stream>>>(h1f8, as1, ad1, offsets, csr, b1, N, h2in);

    // layer 2 (h2 bf16)
    k_gemm_att<64, 1, true, false><<<(N + 127) / 128, 256, 0, stream>>>(
        h2in, W2t, att_s2, att_d2, N, h2bf, as2, ad2);
    k_agg2<<<(N * 32 + 255) / 256, 256, 0, stream>>>(h2bf, as2, ad2, offsets, csr, b2,
                                                     N, (float*)d_out);
}

// Round 18
// 132.816 us; speedup vs baseline: 1.2197x; 1.2197x over previous
//
#include <hip/hip_runtime.h>
#include <math.h>

#define IN_CH 128
#define H1N 8
#define C1N 16
#define C2N 64
#define NEG_SLOPE 0.2f

#define BKT_SHIFT 7                 // 128 nodes per bucket
#define BKT_NODES (1 << BKT_SHIFT)
#define NBLK 128                    // blocks for count/bin passes

typedef unsigned short ushortT;
typedef unsigned char ucharT;
typedef short bf16x8 __attribute__((ext_vector_type(8)));
typedef float f32x4 __attribute__((ext_vector_type(4)));
typedef ushortT us8 __attribute__((ext_vector_type(8)));

__device__ __forceinline__ ushortT f2bf(float f) {
    unsigned u = __float_as_uint(f);
    unsigned r = u + 0x7FFFu + ((u >> 16) & 1u);
    return (ushortT)(r >> 16);
}
__device__ __forceinline__ float bf2f(ushortT b) {
    return __uint_as_float(((unsigned)b) << 16);
}
__device__ __forceinline__ float leaky(float x) {
    return (x > 0.f) ? x : NEG_SLOPE * x;
}
__device__ __forceinline__ ucharT f2fp8(float f) {
    unsigned r = (unsigned)__builtin_amdgcn_cvt_pk_fp8_f32(f, 0.f, 0, false);
    return (ucharT)(r & 0xFFu);
}

// ---------------- CSR build: deterministic counting sort, no global atomics ----------------

__global__ __launch_bounds__(512) void k_cnt(const int* __restrict__ dst,
                                             int E, int N, int* __restrict__ cnt) {
    __shared__ int hist[512];
    int blk = blockIdx.x, t = threadIdx.x;
    int nb = (N + BKT_NODES - 1) >> BKT_SHIFT;
    if (t < nb) hist[t] = 0;
    __syncthreads();
    int Etot = E + N;
    int chunk = (Etot + gridDim.x - 1) / gridDim.x;
    int lo = blk * chunk;
    int hi = lo + chunk; if (hi > Etot) hi = Etot;
    for (int i = lo + t; i < hi; i += 512) {
        int d = (i < E) ? dst[i] : (i - E);
        atomicAdd(&hist[d >> BKT_SHIFT], 1);
    }
    __syncthreads();
    if (t < nb) cnt[t * NBLK + blk] = hist[t];
}

__global__ __launch_bounds__(NBLK) void k_scanrel(int* __restrict__ cnt,
                                                  int* __restrict__ bucketTotal) {
    __shared__ int sh[NBLK];
    int b = blockIdx.x, t = threadIdx.x;
    sh[t] = cnt[b * NBLK + t];
    __syncthreads();
    for (int off = 1; off < NBLK; off <<= 1) {
        int v = (t >= off) ? sh[t - off] : 0;
        __syncthreads();
        sh[t] += v;
        __syncthreads();
    }
    if (t == NBLK - 1) bucketTotal[b] = sh[t];
    cnt[b * NBLK + t] = (t == 0) ? 0 : sh[t - 1];
}

__global__ __launch_bounds__(512) void k_scanbucket(const int* __restrict__ bucketTotal,
                                                    int nb, int* __restrict__ bBase,
                                                    int N, int* __restrict__ offsets) {
    __shared__ int sh[512];
    int t = threadIdx.x;
    sh[t] = (t < nb) ? bucketTotal[t] : 0;
    __syncthreads();
    for (int off = 1; off < 512; off <<= 1) {
        int v = (t >= off) ? sh[t - off] : 0;
        __syncthreads();
        sh[t] += v;
        __syncthreads();
    }
    if (t < nb) bBase[t] = (t == 0) ? 0 : sh[t - 1];
    if (t == 511) { bBase[nb] = sh[511]; offsets[N] = sh[511]; }
}

__global__ __launch_bounds__(512) void k_bin(const int* __restrict__ src,
                                             const int* __restrict__ dst,
                                             int E, int N,
                                             const int* __restrict__ cnt,
                                             const int* __restrict__ bBase,
                                             unsigned* __restrict__ pair) {
    __shared__ int cur[512];
    int blk = blockIdx.x, t = threadIdx.x;
    int nb = (N + BKT_NODES - 1) >> BKT_SHIFT;
    if (t < nb) cur[t] = bBase[t] + cnt[t * NBLK + blk];
    __syncthreads();
    int Etot = E + N;
    int chunk = (Etot + gridDim.x - 1) / gridDim.x;
    int lo = blk * chunk;
    int hi = lo + chunk; if (hi > Etot) hi = Etot;
    for (int i = lo + t; i < hi; i += 512) {
        int s, d;
        if (i < E) { s = src[i]; d = dst[i]; }
        else       { s = d = i - E; }
        int b = d >> BKT_SHIFT;
        int pos = atomicAdd(&cur[b], 1);
        pair[pos] = ((unsigned)(d & (BKT_NODES - 1)) << 16) | (unsigned)s;
    }
}

__global__ __launch_bounds__(256) void k_csr_local(const unsigned* __restrict__ pair,
                                                   const int* __restrict__ bBase,
                                                   int N, int* __restrict__ offsets,
                                                   ushortT* __restrict__ csr) {
    __shared__ int hist[BKT_NODES];
    __shared__ int loff[BKT_NODES];
    int b = blockIdx.x;
    int t = threadIdx.x;
    int base = bBase[b];
    int cnt = bBase[b + 1] - base;
    const unsigned* pp = pair + base;

    if (t < BKT_NODES) hist[t] = 0;
    __syncthreads();
    for (int i = t; i < cnt; i += 256) atomicAdd(&hist[pp[i] >> 16], 1);
    __syncthreads();
    if (t < BKT_NODES) loff[t] = hist[t];
    __syncthreads();
    for (int off = 1; off < BKT_NODES; off <<= 1) {
        int v = 0;
        if (t < BKT_NODES && t >= off) v = loff[t - off];
        __syncthreads();
        if (t < BKT_NODES) loff[t] += v;
        __syncthreads();
    }
    int node0 = b << BKT_SHIFT;
    if (t < BKT_NODES) {
        int excl = (t == 0) ? 0 : loff[t - 1];
        hist[t] = excl;
        int g = node0 + t;
        if (g < N) offsets[g] = base + excl;
    }
    __syncthreads();
    for (int i = t; i < cnt; i += 256) {
        unsigned pk = pp[i];
        int pos = atomicAdd(&hist[pk >> 16], 1);
        csr[base + pos] = (ushortT)(pk & 0xFFFFu);
    }
}

// ---------------- one-shot W transpose+cast (both weights in one launch) ----------------

__global__ void k_wcast(const float* __restrict__ W1, const float* __restrict__ W2,
                        ushortT* __restrict__ W1t, ushortT* __restrict__ W2t) {
    int id = blockIdx.x * blockDim.x + threadIdx.x;
    if (id < IN_CH * IN_CH) {
        int n = id / IN_CH, k = id % IN_CH;
        W1t[id] = f2bf(W1[(size_t)k * IN_CH + n]);
    } else if (id < IN_CH * IN_CH + IN_CH * C2N) {
        int id2 = id - IN_CH * IN_CH;
        int n = id2 / IN_CH, k = id2 % IN_CH;
        W2t[id2] = f2bf(W2[(size_t)k * C2N + n]);
    }
}

// ---------------- MFMA GEMM (bf16) + fused attention coefficients ----------------
// C = A @ W; BM=128 rows/block, 4 waves x 2 strips; W pre-transposed bf16.
// OUT8: store C as fp8 e4m3; else bf16.
// C/D layout: col=lane&15, row=(lane>>4)*4+reg (validated R13).

template <int KOUT, int HEADS, bool BFIN, bool OUT8>
__global__ __launch_bounds__(256) void k_gemm_att(const void* __restrict__ Av,
                                                  const ushortT* __restrict__ Wt,
                                                  const float* __restrict__ att_s,
                                                  const float* __restrict__ att_d,
                                                  int N, void* __restrict__ Cout,
                                                  float* __restrict__ as_,
                                                  float* __restrict__ ad_) {
    constexpr int NT = KOUT / 16;
    constexpr int LDK = IN_CH + 8;
    __shared__ ushortT Alds[128][LDK];
    __shared__ ushortT Wlds[KOUT][LDK];
    int t = threadIdx.x;
    int row0 = blockIdx.x * 128;
    int w    = t >> 6;
    int lane = t & 63;
    int lm   = lane & 15;
    int lg   = lane >> 4;

    if constexpr (BFIN) {
        for (int idx = t; idx < 128 * 16; idx += 256) {
            int r  = idx >> 4;
            int c8 = (idx & 15) << 3;
            int gr = row0 + r;
            us8 u = (us8){0,0,0,0,0,0,0,0};
            if (gr < N) u = *(const us8*)((const ushortT*)Av + (size_t)gr * IN_CH + c8);
            *(us8*)(&Alds[r][c8]) = u;
        }
    } else {
        for (int idx = t; idx < 128 * 32; idx += 256) {
            int r  = idx >> 5;
            int c4 = (idx & 31) << 2;
            int gr = row0 + r;
            ushort4 u; u.x = 0; u.y = 0; u.z = 0; u.w = 0;
            if (gr < N) {
                float4 v = *(const float4*)((const float*)Av + (size_t)gr * IN_CH + c4);
                u.x = f2bf(v.x); u.y = f2bf(v.y); u.z = f2bf(v.z); u.w = f2bf(v.w);
            }
            *(ushort4*)(&Alds[r][c4]) = u;
        }
    }
    for (int idx = t; idx < KOUT * 16; idx += 256) {
        int n  = idx >> 4;
        int kb = (idx & 15) << 3;
        *(us8*)(&Wlds[n][kb]) = *(const us8*)(Wt + (size_t)n * IN_CH + kb);
    }
    __syncthreads();

    f32x4 acc[2][NT];
#pragma unroll
    for (int s = 0; s < 2; ++s)
#pragma unroll
        for (int ct = 0; ct < NT; ++ct) acc[s][ct] = (f32x4){0.f, 0.f, 0.f, 0.f};

#pragma unroll
    for (int s = 0; s < 2; ++s) {
        int ar = w * 32 + s * 16 + lm;
#pragma unroll
        for (int ks = 0; ks < 4; ++ks) {
            int kb = ks * 32 + lg * 8;
            bf16x8 af = *(const bf16x8*)(&Alds[ar][kb]);
#pragma unroll
            for (int ct = 0; ct < NT; ++ct) {
                bf16x8 bf = *(const bf16x8*)(&Wlds[ct * 16 + lm][kb]);
                acc[s][ct] = __builtin_amdgcn_mfma_f32_16x16x32_bf16(af, bf, acc[s][ct], 0, 0, 0);
            }
        }
    }

#pragma unroll
    for (int s = 0; s < 2; ++s) {
        int rb = row0 + w * 32 + s * 16 + lg * 4;
        float asp0 = 0.f, asp1 = 0.f, asp2 = 0.f, asp3 = 0.f;
        float adp0 = 0.f, adp1 = 0.f, adp2 = 0.f, adp3 = 0.f;
#pragma unroll
        for (int ct = 0; ct < NT; ++ct) {
            int gcol = ct * 16 + lm;
            float sc = att_s[gcol];
            float dc = att_d[gcol];
            float c0 = acc[s][ct][0], c1 = acc[s][ct][1];
            float c2 = acc[s][ct][2], c3 = acc[s][ct][3];
#pragma unroll
            for (int i = 0; i < 4; ++i) {
                int gr = rb + i;
                if (gr < N) {
                    if constexpr (OUT8) {
                        ((ucharT*)Cout)[(size_t)gr * KOUT + gcol] = f2fp8(acc[s][ct][i]);
                    } else {
                        ((ushortT*)Cout)[(size_t)gr * KOUT + gcol] = f2bf(acc[s][ct][i]);
                    }
                }
            }
            if constexpr (HEADS == 1) {
                asp0 = fmaf(c0, sc, asp0); asp1 = fmaf(c1, sc, asp1);
                asp2 = fmaf(c2, sc, asp2); asp3 = fmaf(c3, sc, asp3);
                adp0 = fmaf(c0, dc, adp0); adp1 = fmaf(c1, dc, adp1);
                adp2 = fmaf(c2, dc, adp2); adp3 = fmaf(c3, dc, adp3);
            } else {
                float r0 = c0 * sc, r1 = c1 * sc, r2 = c2 * sc, r3 = c3 * sc;
                float q0 = c0 * dc, q1 = c1 * dc, q2 = c2 * dc, q3 = c3 * dc;
#pragma unroll
                for (int off = 1; off < 16; off <<= 1) {
                    r0 += __shfl_xor(r0, off); r1 += __shfl_xor(r1, off);
                    r2 += __shfl_xor(r2, off); r3 += __shfl_xor(r3, off);
                    q0 += __shfl_xor(q0, off); q1 += __shfl_xor(q1, off);
                    q2 += __shfl_xor(q2, off); q3 += __shfl_xor(q3, off);
                }
                if (lm == 0) {
                    if (rb + 0 < N) { as_[(size_t)(rb + 0) * HEADS + ct] = r0; ad_[(size_t)(rb + 0) * HEADS + ct] = q0; }
                    if (rb + 1 < N) { as_[(size_t)(rb + 1) * HEADS + ct] = r1; ad_[(size_t)(rb + 1) * HEADS + ct] = q1; }
                    if (rb + 2 < N) { as_[(size_t)(rb + 2) * HEADS + ct] = r2; ad_[(size_t)(rb + 2) * HEADS + ct] = q2; }
                    if (rb + 3 < N) { as_[(size_t)(rb + 3) * HEADS + ct] = r3; ad_[(size_t)(rb + 3) * HEADS + ct] = q3; }
                }
            }
        }
        if constexpr (HEADS == 1) {
#pragma unroll
            for (int off = 1; off < 16; off <<= 1) {
                asp0 += __shfl_xor(asp0, off); asp1 += __shfl_xor(asp1, off);
                asp2 += __shfl_xor(asp2, off); asp3 += __shfl_xor(asp3, off);
                adp0 += __shfl_xor(adp0, off); adp1 += __shfl_xor(adp1, off);
                adp2 += __shfl_xor(adp2, off); adp3 += __shfl_xor(adp3, off);
            }
            if (lm == 0) {
                if (rb + 0 < N) { as_[rb + 0] = asp0; ad_[rb + 0] = adp0; }
                if (rb + 1 < N) { as_[rb + 1] = asp1; ad_[rb + 1] = adp1; }
                if (rb + 2 < N) { as_[rb + 2] = asp2; ad_[rb + 2] = adp2; }
                if (rb + 3 < N) { as_[rb + 3] = asp3; ad_[rb + 3] = adp3; }
            }
        }
    }
}

// ---------------- layer 1 aggregation (+bias +ELU) ----------------
// h1 fp8 e4m3 (128 B/row); lane reads ushort = 2 fp8, HW cvt. Output bf16.

__global__ void k_agg1(const ucharT* __restrict__ h1f8,
                       const float* __restrict__ as1, const float* __restrict__ ad1,
                       const int* __restrict__ offsets, const ushortT* __restrict__ csr,
                       const float* __restrict__ b1,
                       int N, ushortT* __restrict__ h2in) {
    int wid  = (blockIdx.x * blockDim.x + threadIdx.x) >> 6;
    int lane = threadIdx.x & 63;
    if (wid >= N) return;
    int v = wid;
    int hc = lane >> 3;
    int hp = lane & 7;
    float adc = ad1[v * H1N + hc];
    float adp = ad1[v * H1N + hp];
    float denom = 0.f, acc0 = 0.f, acc1 = 0.f;
    int beg = offsets[v], end = offsets[v + 1];
    int j = beg;
    for (; j + 8 <= end; j += 8) {
        int ep = lane >> 3;
        int sE = csr[j + ep];
        float a = as1[sE * H1N + hp];
        float pp = __expf(leaky(a + adp));
#pragma unroll
        for (int e = 0; e < 8; ++e) {
            int srcl = e * 8 + hc;
            float pe = __shfl(pp, srcl);
            int   se = __shfl(sE, srcl);
            unsigned q = *(const ushortT*)(h1f8 + (size_t)se * IN_CH + lane * 2);
            float x0 = __builtin_amdgcn_cvt_f32_fp8(q, 0);
            float x1 = __builtin_amdgcn_cvt_f32_fp8(q, 1);
            denom += pe;
            acc0 = fmaf(pe, x0, acc0);
            acc1 = fmaf(pe, x1, acc1);
        }
    }
    if (j + 4 <= end) {
        int ep = (lane >> 3) & 3;
        int sE = csr[j + ep];
        float a = as1[sE * H1N + hp];
        float pp = __expf(leaky(a + adp));
#pragma unroll
        for (int e = 0; e < 4; ++e) {
            int srcl = e * 8 + hc;
            float pe = __shfl(pp, srcl);
            int   se = __shfl(sE, srcl);
            unsigned q = *(const ushortT*)(h1f8 + (size_t)se * IN_CH + lane * 2);
            float x0 = __builtin_amdgcn_cvt_f32_fp8(q, 0);
            float x1 = __builtin_amdgcn_cvt_f32_fp8(q, 1);
            denom += pe;
            acc0 = fmaf(pe, x0, acc0);
            acc1 = fmaf(pe, x1, acc1);
        }
        j += 4;
    }
    for (; j < end; ++j) {
        int s = csr[j];
        float a = as1[s * H1N + hc];
        unsigned q = *(const ushortT*)(h1f8 + (size_t)s * IN_CH + lane * 2);
        float x0 = __builtin_amdgcn_cvt_f32_fp8(q, 0);
        float x1 = __builtin_amdgcn_cvt_f32_fp8(q, 1);
        float p = __expf(leaky(a + adc));
        denom += p;
        acc0 = fmaf(p, x0, acc0);
        acc1 = fmaf(p, x1, acc1);
    }
    float inv = 1.f / (denom + 1e-16f);
    float o0 = acc0 * inv + b1[lane * 2];
    float o1 = acc1 * inv + b1[lane * 2 + 1];
    o0 = (o0 > 0.f) ? o0 : expm1f(o0);
    o1 = (o1 > 0.f) ? o1 : expm1f(o1);
    unsigned pk = ((unsigned)f2bf(o1) << 16) | (unsigned)f2bf(o0);
    *(unsigned*)(h2in + (size_t)v * IN_CH + lane * 2) = pk;
}

// ---------------- layer 2 aggregation (+bias) + log_softmax ----------------

__global__ __launch_bounds__(256) void k_agg2(const ushortT* __restrict__ h2bf,
                       const float* __restrict__ as2, const float* __restrict__ ad2,
                       const int* __restrict__ offsets, const ushortT* __restrict__ csr,
                       const float* __restrict__ b2,
                       int N, float* __restrict__ out) {
    int wid  = (blockIdx.x * blockDim.x + threadIdx.x) >> 6;
    int lane = threadIdx.x & 63;
    int half = lane >> 5;
    int v = wid * 2 + half;
    bool alive = (v < N);
    int c2 = (lane & 31) * 2;

    float ad = 0.f;
    int beg = 0, end = 0;
    if (alive) {
        ad = ad2[v];
        beg = offsets[v];
        end = offsets[v + 1];
    }
    float denom = 0.f, acc0 = 0.f, acc1 = 0.f;
    int j = beg;
    for (; j + 8 <= end; j += 8) {
        int sE = csr[j + (lane & 7)];
        float p = __expf(leaky(as2[sE] + ad));
#pragma unroll
        for (int e = 0; e < 8; ++e) {
            int srcl = (lane & 32) + e;
            float pe = __shfl(p, srcl);
            int   se = __shfl(sE, srcl);
            unsigned q = *(const unsigned*)(h2bf + (size_t)se * C2N + c2);
            denom += pe;
            acc0 = fmaf(pe, bf2f((ushortT)(q & 0xFFFFu)), acc0);
            acc1 = fmaf(pe, bf2f((ushortT)(q >> 16)), acc1);
        }
    }
    if (j < end) {
        int m = end - j;
        int ep = lane & 7;
        int sE = 0;
        float p = 0.f;
        if (ep < m) {
            sE = csr[j + ep];
            p = __expf(leaky(as2[sE] + ad));
        }
        for (int e = 0; e < m; ++e) {
            int srcl = (lane & 32) + e;
            float pe = __shfl(p, srcl);
            int   se = __shfl(sE, srcl);
            unsigned q = *(const unsigned*)(h2bf + (size_t)se * C2N + c2);
            denom += pe;
            acc0 = fmaf(pe, bf2f((ushortT)(q & 0xFFFFu)), acc0);
            acc1 = fmaf(pe, bf2f((ushortT)(q >> 16)), acc1);
        }
    }
    float inv = 1.f / (denom + 1e-16f);
    float o0 = acc0 * inv + b2[c2];
    float o1 = acc1 * inv + b2[c2 + 1];
    float mx = fmaxf(o0, o1);
#pragma unroll
    for (int off = 16; off >= 1; off >>= 1) mx = fmaxf(mx, __shfl_xor(mx, off));
    float se2 = __expf(o0 - mx) + __expf(o1 - mx);
#pragma unroll
    for (int off = 16; off >= 1; off >>= 1) se2 += __shfl_xor(se2, off);
    if (alive) {
        float lse = logf(se2);
        float2 ov; ov.x = o0 - mx - lse; ov.y = o1 - mx - lse;
        *(float2*)(out + (size_t)v * C2N + c2) = ov;
    }
}

// ---------------- launch ----------------

extern "C" void kernel_launch(void* const* d_in, const int* in_sizes, int n_in,
                              void* d_out, int out_size, void* d_ws, size_t ws_size,
                              hipStream_t stream) {
    const float* x      = (const float*)d_in[0];
    const int*   ei     = (const int*)d_in[1];
    const float* W1     = (const float*)d_in[2];
    const float* att_s1 = (const float*)d_in[3];
    const float* att_d1 = (const float*)d_in[4];
    const float* b1     = (const float*)d_in[5];
    const float* W2     = (const float*)d_in[6];
    const float* att_s2 = (const float*)d_in[7];
    const float* att_d2 = (const float*)d_in[8];
    const float* b2     = (const float*)d_in[9];

    int N = in_sizes[0] / IN_CH;
    int E = in_sizes[1] / 2;
    const int* srcA = ei;
    const int* dstA = ei + E;
    int Etot = E + N;
    int nb = (N + BKT_NODES - 1) >> BKT_SHIFT;

    char* p = (char*)d_ws;
    auto carve = [&](size_t bytes) {
        void* r = (void*)p;
        p += (bytes + 255) & ~(size_t)255;
        return r;
    };
    ucharT* h1f8  = (ucharT*)carve((size_t)N * IN_CH);
    ushortT* h2bf = (ushortT*)carve((size_t)N * C2N * 2);
    ushortT* h2in = (ushortT*)carve((size_t)N * IN_CH * 2);
    float* as1  = (float*)carve((size_t)N * H1N * 4);
    float* ad1  = (float*)carve((size_t)N * H1N * 4);
    float* as2  = (float*)carve((size_t)N * 4);
    float* ad2  = (float*)carve((size_t)N * 4);
    int* offsets     = (int*)carve((size_t)(N + 1) * 4);
    ushortT* csr     = (ushortT*)carve((size_t)(Etot + 32) * 2);
    int* cnt         = (int*)carve((size_t)nb * NBLK * 4);
    int* bucketTotal = (int*)carve((size_t)nb * 4);
    int* bBase       = (int*)carve((size_t)(nb + 1) * 4);
    unsigned* pair   = (unsigned*)carve((size_t)Etot * 4);
    ushortT* W1t     = (ushortT*)carve((size_t)IN_CH * IN_CH * 2);
    ushortT* W2t     = (ushortT*)carve((size_t)IN_CH * C2N * 2);

    // one-shot weight transpose+cast (both weights, one launch)
    k_wcast<<<(IN_CH * IN_CH + IN_CH * C2N + 255) / 256, 256, 0, stream>>>(W1, W2, W1t, W2t);

    // CSR build (deterministic counting sort; no global atomics, no memsets)
    k_cnt<<<NBLK, 512, 0, stream>>>(dstA, E, N, cnt);
    k_scanrel<<<nb, NBLK, 0, stream>>>(cnt, bucketTotal);
    k_scanbucket<<<1, 512, 0, stream>>>(bucketTotal, nb, bBase, N, offsets);
    k_bin<<<NBLK, 512, 0, stream>>>(srcA, dstA, E, N, cnt, bBase, pair);
    k_csr_local<<<nb, 256, 0, stream>>>(pair, bBase, N, offsets, csr);

    // layer 1 (h1 stored fp8 e4m3)
    k_gemm_att<128, 8, false, true><<<(N + 127) / 128, 256, 0, stream>>>(
        x, W1t, att_s1, att_d1, N, h1f8, as1, ad1);
    k_agg1<<<(N * 64 + 255) / 256, 256, 0, stream>>>(h1f8, as1, ad1, offsets, csr, b1, N, h2in);

    // layer 2 (h2 bf16)
    k_gemm_att<64, 1, true, false><<<(N + 127) / 128, 256, 0, stream>>>(
        h2in, W2t, att_s2, att_d2, N, h2bf, as2, ad2);
    k_agg2<<<(N * 32 + 255) / 256, 256, 0, stream>>>(h2bf, as2, ad2, offsets, csr, b2,
                                                     N, (float*)d_out);
}